// Round 7
// baseline (1305.808 us; speedup 1.0000x reference)
//
#include <hip/hip_runtime.h>
#include <math.h>

#define DD 512
#define NBLKA 400

#define PM 128          // prefilter tile rows
#define PN 128          // prefilter tile cols
#define KB 64           // k-chunk (two MFMA K-steps per chunk)
#define CSPLIT 6        // column splits -> 480 blocks = exactly 2/CU, no tail
#define NC 12           // candidates kept per row per split (>= k=9)
#define NCTOT (CSPLIT*NC)   // 72 candidates per row total
#define KOUTMAX 16
#define RS_MARGIN 2e-4f     // rescore prune margin (bf16 score err bound ~3e-5)

typedef __attribute__((ext_vector_type(8))) short bf16x8;   // 8 bf16 = 4 VGPR
typedef __attribute__((ext_vector_type(4))) float f32x4;    // MFMA 16x16 accumulator

static __device__ __forceinline__ unsigned short f2bf(float f) {
    unsigned u = __float_as_uint(f);
    u += 0x7fff + ((u >> 16) & 1);      // round-to-nearest-even
    return (unsigned short)(u >> 16);
}

// branchless-ish top-NC register insert, static indexing (rule #20)
#define INSERT_CAND(LS, LI, SV, JJ)                                           \
    do {                                                                      \
        if ((SV) < LS[NC-1] || ((SV) == LS[NC-1] && (JJ) < LI[NC-1])) {       \
            float cs_ = (SV); int cj_ = (JJ);                                 \
            _Pragma("unroll")                                                 \
            for (int p_ = 0; p_ < NC; ++p_) {                                 \
                bool lt_ = (cs_ < LS[p_]) || (cs_ == LS[p_] && cj_ < LI[p_]); \
                float ts_ = LS[p_]; int tj_ = LI[p_];                         \
                if (lt_) { LS[p_] = cs_; LI[p_] = cj_; cs_ = ts_; cj_ = tj_; }\
            }                                                                 \
        }                                                                     \
    } while (0)

// ---------------- Kernel A1: partial column sums of x^2 (fp64, deterministic) ----------------
__global__ void colsum_partial(const float* __restrict__ x, double* __restrict__ partial,
                               int N, int rows_per_block) {
    int b = blockIdx.x;
    int t = threadIdx.x;
    int r0 = b * rows_per_block;
    int r1 = min(r0 + rows_per_block, N);
    double s0 = 0.0, s1 = 0.0;
    for (int r = r0; r < r1; ++r) {
        float v0 = x[(size_t)r * DD + t];
        float v1 = x[(size_t)r * DD + t + 256];
        s0 += (double)v0 * (double)v0;
        s1 += (double)v1 * (double)v1;
    }
    partial[(size_t)b * DD + t]       = s0;
    partial[(size_t)b * DD + t + 256] = s1;
}

// ---------------- Kernel A2: rn=1/max(sqrt(s),eps) fp64, w=rn*rn fp64 ----------------
__global__ void colnorm_finish(const double* __restrict__ partial, double* __restrict__ rn,
                               double* __restrict__ w, int nblk) {
    int c = threadIdx.x;                 // 512 threads
    double s = 0.0;
    for (int b = 0; b < nblk; ++b) s += partial[(size_t)b * DD + c];
    double n = fmax(sqrt(s), 1e-12);
    double r = 1.0 / n;
    rn[c]  = r;
    w[c]   = r * r;
}

// ---------------- Kernel B: sq[i] fp64, sqf[i] fp32, xnbf[i][:] bf16 ----------------
__global__ void row_sq(const float* __restrict__ x, const double* __restrict__ rn,
                       double* __restrict__ sq, float* __restrict__ sqf,
                       unsigned short* __restrict__ xnbf, int N) {
    int i = blockIdx.x;
    int t = threadIdx.x;
    double a0 = (double)x[(size_t)i * DD + t]       * rn[t];
    double a1 = (double)x[(size_t)i * DD + t + 256] * rn[t + 256];
    xnbf[(size_t)i * DD + t]       = f2bf((float)a0);
    xnbf[(size_t)i * DD + t + 256] = f2bf((float)a1);
    double local = a0 * a0 + a1 * a1;
    __shared__ double red[256];
    red[t] = local;
    __syncthreads();
    for (int off = 128; off > 0; off >>= 1) {
        if (t < off) red[t] += red[t + off];
        __syncthreads();
    }
    if (t == 0) { sq[i] = red[0]; sqf[i] = (float)red[0]; }
}

// ---------------- Kernel C: bf16 MFMA prefilter, wave-local register top-k ----------------
// R7 = R6 + one trailing __syncthreads() per tile (fixes the sqj_s
// read->overwrite race: R6's register-only selection had no barrier between
// a wave's sqj_s reads and the next tile's sqj_s write by faster waves).
// Structure: swapped-operand MFMA (C[j][i] = mfma(B_frag, A_frag)) so C's
// column (lane&15) indexes output ROW i; each lane keeps per-subset top-NC
// lists in registers; once per split, lanes {l,l^16,l^32,l^48} (disjoint
// j-subsets) xor-converge-merge. No LDS atomics, no round protocol.
// K-loop: counted-vmcnt double-buffer + 16B-granule XOR swizzle c^=(row&3).
__global__ __launch_bounds__(256, 2) void gemm_prefilter(
    const unsigned short* __restrict__ xnbf,
    const float* __restrict__ sqf, int* __restrict__ cand, float* __restrict__ cands,
    int N, int ntileM, int ntileN)
{
    // A0 @0, A1 @16384, B0 @32768, B1 @49152 (each 16 KB, chunk kstep-major)
    __shared__ __align__(16) unsigned char lds_raw[65536];
    __shared__ float sqj_s[PN];           // ~64.5 KB total -> 2 blocks/CU

    const int bid   = blockIdx.x;
    const int q     = bid & 7;
    const int s     = bid >> 3;
    const int ridx  = s / CSPLIT;
    const int split = s - ridx * CSPLIT;
    const int rowb  = q + 8 * ridx;
    if (rowb >= ntileM) return;                   // uniform early exit (pad blocks)
    const int row0  = rowb * PM;

    const int t      = threadIdx.x;
    const int lane15 = t & 15;
    const int quad   = (t >> 4) & 3;              // (lane>>4)&3
    const int wave   = t >> 6;
    const int i0     = wave * 32;                 // wave's 32-row i-strip
    const int rg4    = quad * 4;                  // j sub-offset within a j-tile
    const int cq8    = (quad ^ (lane15 & 3)) * 8; // swizzled k-group read offset

    // per-lane subset top-NC lists for the 2 rows this lane owns
    float ls0[NC], ls1[NC];
    int   li0[NC], li1[NC];
#pragma unroll
    for (int m = 0; m < NC; ++m) {
        ls0[m] = __builtin_inff(); li0[m] = 0x7fffffff;
        ls1[m] = __builtin_inff(); li1[m] = 0x7fffffff;
    }

    f32x4 acc[8][2];                              // [j-tile][i-tile]

    for (int tile = split; tile < ntileN; tile += CSPLIT) {
        int col0 = tile * PN;

        if (t < PN) {
            int j = col0 + t;
            sqj_s[t] = (j < N) ? sqf[j] : __builtin_inff();
        }
        __syncthreads();   // sqj write visible to all before k-loop/selection

#pragma unroll
        for (int jt = 0; jt < 8; ++jt)
#pragma unroll
            for (int it = 0; it < 2; ++it)
                acc[jt][it] = (f32x4){0.f, 0.f, 0.f, 0.f};

        // DMA one chunk (A+B, 8 wave-instrs) into buffer buf.
        // 16B-granule source swizzle: LDS slot (row,c) holds global chunk c^(row&3).
        auto STAGE = [&](int kc, int buf) {
#pragma unroll
            for (int l = 0; l < 4; ++l) {
                int e    = t + l * 256;           // 0..1023 (16B chunks)
                int half = e >> 9;                // kstep half
                int re   = e & 511;
                int row  = re >> 2;
                int c    = (re & 3) ^ (row & 3);  // pre-swizzled global chunk
                size_t gA = (size_t)(row0 + row) * DD + kc + half * 32 + c * 8;
                __builtin_amdgcn_global_load_lds(
                    (const unsigned int*)(xnbf + gA),
                    (unsigned int*)(lds_raw + (size_t)buf * 16384 + (size_t)e * 16), 16, 0, 0);
                size_t gB = (size_t)(col0 + row) * DD + kc + half * 32 + c * 8;
                __builtin_amdgcn_global_load_lds(
                    (const unsigned int*)(xnbf + gB),
                    (unsigned int*)(lds_raw + 32768 + (size_t)buf * 16384 + (size_t)e * 16), 16, 0, 0);
            }
        };

        STAGE(0, 0);                               // prologue prefetch
#pragma unroll 1
        for (int cc = 0; cc < 8; ++cc) {
            if (cc < 7) {
                STAGE((cc + 1) * KB, (cc + 1) & 1);      // prefetch next chunk
                __builtin_amdgcn_sched_barrier(0);
                asm volatile("s_waitcnt vmcnt(8)" ::: "memory");  // drain chunk cc only
            } else {
                __builtin_amdgcn_sched_barrier(0);
                asm volatile("s_waitcnt vmcnt(0)" ::: "memory");  // last chunk: drain all
            }
            __builtin_amdgcn_s_barrier();          // chunk cc staged for all waves
            __builtin_amdgcn_sched_barrier(0);

            const unsigned short (*Ab)[PM][32] =
                (const unsigned short (*)[PM][32])(lds_raw + (size_t)(cc & 1) * 16384);
            const unsigned short (*Bb)[PN][32] =
                (const unsigned short (*)[PN][32])(lds_raw + 32768 + (size_t)(cc & 1) * 16384);
#pragma unroll
            for (int ks = 0; ks < 2; ++ks) {
                bf16x8 bj[8], ai[2];
#pragma unroll
                for (int jt = 0; jt < 8; ++jt)
                    bj[jt] = *(const bf16x8*)&Bb[ks][jt * 16 + lane15][cq8];
#pragma unroll
                for (int it = 0; it < 2; ++it)
                    ai[it] = *(const bf16x8*)&Ab[ks][i0 + it * 16 + lane15][cq8];
#pragma unroll
                for (int jt = 0; jt < 8; ++jt)
#pragma unroll
                    for (int it = 0; it < 2; ++it)
                        acc[jt][it] = __builtin_amdgcn_mfma_f32_16x16x32_bf16(
                            bj[jt], ai[it], acc[jt][it], 0, 0, 0);
            }
            __builtin_amdgcn_sched_barrier(0);
            __builtin_amdgcn_s_barrier();          // frag reads done before buf re-staged
        }

        // selection epilogue: pure-register, no barriers.
        // lane holds C[j][i]: j = col0 + jt*16 + rg4 + reg, i = row0+i0+it*16+lane15
#pragma unroll
        for (int jt = 0; jt < 8; ++jt) {
            const float4 sq4 = *(const float4*)&sqj_s[jt * 16 + rg4];
            const int jb = col0 + jt * 16 + rg4;
            {   // it = 0
                float s0 = fmaf(-2.f, acc[jt][0][0], sq4.x);
                float s1 = fmaf(-2.f, acc[jt][0][1], sq4.y);
                float s2 = fmaf(-2.f, acc[jt][0][2], sq4.z);
                float s3 = fmaf(-2.f, acc[jt][0][3], sq4.w);
                float mn = fminf(fminf(s0, s1), fminf(s2, s3));
                if (mn <= ls0[NC - 1]) {
                    if (jb + 0 < N) INSERT_CAND(ls0, li0, s0, jb + 0);
                    if (jb + 1 < N) INSERT_CAND(ls0, li0, s1, jb + 1);
                    if (jb + 2 < N) INSERT_CAND(ls0, li0, s2, jb + 2);
                    if (jb + 3 < N) INSERT_CAND(ls0, li0, s3, jb + 3);
                }
            }
            {   // it = 1
                float s0 = fmaf(-2.f, acc[jt][1][0], sq4.x);
                float s1 = fmaf(-2.f, acc[jt][1][1], sq4.y);
                float s2 = fmaf(-2.f, acc[jt][1][2], sq4.z);
                float s3 = fmaf(-2.f, acc[jt][1][3], sq4.w);
                float mn = fminf(fminf(s0, s1), fminf(s2, s3));
                if (mn <= ls1[NC - 1]) {
                    if (jb + 0 < N) INSERT_CAND(ls1, li1, s0, jb + 0);
                    if (jb + 1 < N) INSERT_CAND(ls1, li1, s1, jb + 1);
                    if (jb + 2 < N) INSERT_CAND(ls1, li1, s2, jb + 2);
                    if (jb + 3 < N) INSERT_CAND(ls1, li1, s3, jb + 3);
                }
            }
        }
        __syncthreads();   // R7 fix: selection's sqj_s reads done before next tile's write
    }

    // end-of-split: xor-converge merge across the 4 disjoint lane subsets
    // (l>>4 groups) of each row; all 4 lanes converge to the exact top-NC.
#pragma unroll
    for (int r = 0; r < 2; ++r) {
        const int msk = r ? 32 : 16;
        float os[NC]; int oi[NC];
#pragma unroll
        for (int e = 0; e < NC; ++e) {
            os[e] = __shfl_xor(ls0[e], msk, 64);
            oi[e] = __shfl_xor(li0[e], msk, 64);
        }
#pragma unroll
        for (int e = 0; e < NC; ++e) INSERT_CAND(ls0, li0, os[e], oi[e]);
#pragma unroll
        for (int e = 0; e < NC; ++e) {
            os[e] = __shfl_xor(ls1[e], msk, 64);
            oi[e] = __shfl_xor(li1[e], msk, 64);
        }
#pragma unroll
        for (int e = 0; e < NC; ++e) INSERT_CAND(ls1, li1, os[e], oi[e]);
    }

    // write this split's candidates (index + fp32 s' score)
    if (quad == 0) {
        int ii0 = row0 + i0 + lane15;
        if (ii0 < N) {
#pragma unroll
            for (int m = 0; m < NC; ++m) {
                cand [(size_t)ii0 * NCTOT + split * NC + m] = li0[m];
                cands[(size_t)ii0 * NCTOT + split * NC + m] = ls0[m];
            }
        }
        int ii1 = row0 + i0 + 16 + lane15;
        if (ii1 < N) {
#pragma unroll
            for (int m = 0; m < NC; ++m) {
                cand [(size_t)ii1 * NCTOT + split * NC + m] = li1[m];
                cands[(size_t)ii1 * NCTOT + split * NC + m] = ls1[m];
            }
        }
    }
}

// ---------------- Kernel D: pruned exact fp64 rescore + top-k ----------------
__global__ __launch_bounds__(256) void rescore_topk(
    const float* __restrict__ x, const double* __restrict__ w,
    const double* __restrict__ sq, const int* __restrict__ cand,
    const float* __restrict__ cands, int* __restrict__ out, int N, int k)
{
    __shared__ float Ssc[4][NCTOT];
    int lane = threadIdx.x & 63;
    int wid  = threadIdx.x >> 6;
    int i = blockIdx.x * 4 + wid;
    if (i >= N) return;

    size_t base = (size_t)i * NCTOT;
    Ssc[wid][lane] = cands[base + lane];
    if (lane < NCTOT - 64) Ssc[wid][64 + lane] = cands[base + 64 + lane];

    // 9th-smallest via pivot counting: pivots cover all 72 slots
    float p0 = Ssc[wid][lane];
    float p1 = Ssc[wid][64 + (lane & 7)];
    int c0 = 0, c1 = 0;
    for (int m = 0; m < NCTOT; ++m) {
        float s = Ssc[wid][m];
        c0 += (s <= p0); c1 += (s <= p1);
    }
    float best = __builtin_inff();
    if (c0 >= k) best = p0;
    if (c1 >= k && p1 < best) best = p1;
#pragma unroll
    for (int off = 32; off > 0; off >>= 1)
        best = fminf(best, __shfl_xor(best, off, 64));
    float cut = best + RS_MARGIN;

    double aw[8];
#pragma unroll
    for (int c = 0; c < 8; ++c) {
        int d = lane + 64 * c;
        aw[c] = (double)x[(size_t)i * DD + d] * w[d];
    }
    double sqi = sq[i];

    double bs[KOUTMAX];
    int    bj[KOUTMAX];
    for (int r = 0; r < k; ++r) { bs[r] = __builtin_inf(); bj[r] = 0x7fffffff; }

    int pend = -1;                    // wave-uniform pending candidate index j
    for (int m = 0; m <= NCTOT; ++m) {
        int j1cand = -1;
        if (m < NCTOT) {
            if (Ssc[wid][m] > cut) continue;          // wave-uniform skip
            j1cand = cand[base + m];
            if (pend < 0) { pend = j1cand; continue; } // buffer first of a pair
        } else if (pend < 0) {
            break;                                     // nothing left
        }
        int j0 = pend, j1 = j1cand;
        pend = -1;
        const float* q0 = &x[(size_t)j0 * DD + lane];
        const float* q1 = (j1 >= 0) ? &x[(size_t)j1 * DD + lane] : q0;
        float v0[8], v1[8];
#pragma unroll
        for (int c = 0; c < 8; ++c) v0[c] = q0[64 * c];
#pragma unroll
        for (int c = 0; c < 8; ++c) v1[c] = q1[64 * c];
        double d0 = 0.0, d1 = 0.0;
#pragma unroll
        for (int c = 0; c < 8; ++c) d0 = fma(aw[c], (double)v0[c], d0);
#pragma unroll
        for (int c = 0; c < 8; ++c) d1 = fma(aw[c], (double)v1[c], d1);
#pragma unroll
        for (int off = 32; off > 0; off >>= 1) {
            d0 += __shfl_xor(d0, off, 64);
            d1 += __shfl_xor(d1, off, 64);
        }
        double s0 = (sqi - 2.0 * d0) + sq[j0];
        double s1 = (j1 >= 0) ? (sqi - 2.0 * d1) + sq[j1] : __builtin_inf();
#pragma unroll 1
        for (int pick = 0; pick < 2; ++pick) {
            double sv = pick ? s1 : s0;
            int    j  = pick ? j1 : j0;
            if (j < 0) continue;
            if (sv < bs[k - 1] || (sv == bs[k - 1] && j < bj[k - 1])) {
                int pos = k - 1;
                while (pos > 0) {
                    double ps = bs[pos - 1]; int pj = bj[pos - 1];
                    if (!(sv < ps || (sv == ps && j < pj))) break;
                    bs[pos] = ps; bj[pos] = pj;
                    --pos;
                }
                bs[pos] = sv; bj[pos] = j;
            }
        }
    }
    if (lane == 0) {
        for (int r = 0; r < k; ++r) {
            out[(size_t)i * k + r]                 = bj[r];
            out[(size_t)N * k + (size_t)i * k + r] = i;
        }
    }
}

extern "C" void kernel_launch(void* const* d_in, const int* in_sizes, int n_in,
                              void* d_out, int out_size, void* d_ws, size_t ws_size,
                              hipStream_t stream) {
    const float* x = (const float*)d_in[0];
    int N = in_sizes[0] / DD;            // 10000
    int k = out_size / (2 * N);          // 9
    if (k > KOUTMAX) k = KOUTMAX;

    char* ws = (char*)d_ws;
    double*         partial = (double*)ws;                       // 400*512*8 = 1638400 B
    double*         rn      = (double*)(ws + 1638400);           // 4096 B
    double*         w       = (double*)(ws + 1642496);           // 4096 B
    double*         sq      = (double*)(ws + 1646592);           // 80000 B
    float*          sqf     = (float*) (ws + 1726592);           // 40000 B
    unsigned short* xnbf    = (unsigned short*)(ws + 1766592);   // N*512*2 = 10.24 MB
    int*            cand    = (int*)   (ws + 12006592);          // N*72*4 = 2.88 MB
    float*          cands   = (float*) (ws + 14886592);          // N*72*4 = 2.88 MB

    int rpb = (N + NBLKA - 1) / NBLKA;
    hipLaunchKernelGGL(colsum_partial, dim3(NBLKA), dim3(256), 0, stream, x, partial, N, rpb);
    hipLaunchKernelGGL(colnorm_finish, dim3(1), dim3(512), 0, stream, partial, rn, w, NBLKA);
    hipLaunchKernelGGL(row_sq, dim3(N), dim3(256), 0, stream, x, rn, sq, sqf, xnbf, N);

    int ntileM = (N + PM - 1) / PM;      // 79
    int ntileN = (N + PN - 1) / PN;      // 79
    int rows_per_xcd = (ntileM + 7) / 8; // 10
    int nblk = 8 * rows_per_xcd * CSPLIT; // 480 (pad blocks exit early)
    hipLaunchKernelGGL(gemm_prefilter, dim3(nblk), dim3(256), 0, stream,
                       xnbf, sqf, cand, cands, N, ntileM, ntileN);

    hipLaunchKernelGGL(rescore_topk, dim3((N + 3) / 4), dim3(256), 0, stream,
                       x, w, sq, cand, cands, (int*)d_out, N, k);
}

// Round 9
// 802.156 us; speedup vs baseline: 1.6279x; 1.6279x over previous
//
#include <hip/hip_runtime.h>
#include <math.h>

#define DD 512
#define NBLKA 400

#define PM 128          // prefilter tile rows
#define PN 128          // prefilter tile cols
#define KB 32           // k-chunk (one MFMA K-step per chunk, wave-private)
#define CSPLIT 6        // column splits -> 480 blocks = exactly 2/CU, no tail
#define NC 12           // candidates kept per row per split (>= k=9)
#define PBUF 32         // push buffer per row
#define PBSTRIDE 36     // 36 floats -> 144B rows, 16B aligned
#define NCTOT (CSPLIT*NC)   // 72 candidates per row total
#define KOUTMAX 16
#define RS_MARGIN 2e-4f     // rescore prune margin (bf16 score err bound ~3e-5)

typedef __attribute__((ext_vector_type(8))) short bf16x8;   // 8 bf16 = 4 VGPR
typedef __attribute__((ext_vector_type(4))) float f32x4;    // MFMA 16x16 accumulator

static __device__ __forceinline__ unsigned short f2bf(float f) {
    unsigned u = __float_as_uint(f);
    u += 0x7fff + ((u >> 16) & 1);      // round-to-nearest-even
    return (unsigned short)(u >> 16);
}

// ---------------- Kernel A1: partial column sums of x^2 (fp64, deterministic) ----------------
__global__ void colsum_partial(const float* __restrict__ x, double* __restrict__ partial,
                               int N, int rows_per_block) {
    int b = blockIdx.x;
    int t = threadIdx.x;
    int r0 = b * rows_per_block;
    int r1 = min(r0 + rows_per_block, N);
    double s0 = 0.0, s1 = 0.0;
    for (int r = r0; r < r1; ++r) {
        float v0 = x[(size_t)r * DD + t];
        float v1 = x[(size_t)r * DD + t + 256];
        s0 += (double)v0 * (double)v0;
        s1 += (double)v1 * (double)v1;
    }
    partial[(size_t)b * DD + t]       = s0;
    partial[(size_t)b * DD + t + 256] = s1;
}

// ---------------- Kernel A2: rn=1/max(sqrt(s),eps) fp64, w=rn*rn fp64 ----------------
__global__ void colnorm_finish(const double* __restrict__ partial, double* __restrict__ rn,
                               double* __restrict__ w, int nblk) {
    int c = threadIdx.x;                 // 512 threads
    double s = 0.0;
    for (int b = 0; b < nblk; ++b) s += partial[(size_t)b * DD + c];
    double n = fmax(sqrt(s), 1e-12);
    double r = 1.0 / n;
    rn[c]  = r;
    w[c]   = r * r;
}

// ---------------- Kernel B: sq[i] fp64, sqf[i] fp32, xnbf[i][:] bf16 ----------------
__global__ void row_sq(const float* __restrict__ x, const double* __restrict__ rn,
                       double* __restrict__ sq, float* __restrict__ sqf,
                       unsigned short* __restrict__ xnbf, int N) {
    int i = blockIdx.x;
    int t = threadIdx.x;
    double a0 = (double)x[(size_t)i * DD + t]       * rn[t];
    double a1 = (double)x[(size_t)i * DD + t + 256] * rn[t + 256];
    xnbf[(size_t)i * DD + t]       = f2bf((float)a0);
    xnbf[(size_t)i * DD + t + 256] = f2bf((float)a1);
    double local = a0 * a0 + a1 * a1;
    __shared__ double red[256];
    red[t] = local;
    __syncthreads();
    for (int off = 128; off > 0; off >>= 1) {
        if (t < off) red[t] += red[t + off];
        __syncthreads();
    }
    if (t == 0) { sq[i] = red[0]; sqf[i] = (float)red[0]; }
}

// ---------------- Kernel C: bf16 MFMA prefilter, WAVE-PRIVATE staging (zero k-loop barriers) ----------------
// R8 (resubmitted R9 -- prior run was a container-level infra failure):
// each wave DMAs its OWN 64-row A-slice + 64-col B-slice per KB=32 chunk
// (8KB/chunk/wave, per-wave double buffer = 16KB/wave, 64KB total). All k-loop
// synchronization is s_waitcnt vmcnt(8) -- wave-local -- so the 16 per-tile
// s_barriers of the cooperative scheme are GONE (barrier convoys at 2 waves/
// SIMD were the prime stall suspect). L2 staging traffic doubles (7.6 of
// 34.5 TB/s -- headroom). Granule XOR swizzle c^=(r&3) on the private slices
// (pre-swizzled global source, same involution on read). Selection protocol
// byte-identical to R5; one added __syncthreads (B0) after the k-loop since
// Bsc/Bid alias the staging LDS and the per-chunk barriers no longer exist.
__global__ __launch_bounds__(256, 2) void gemm_prefilter(
    const unsigned short* __restrict__ xnbf,
    const float* __restrict__ sqf, int* __restrict__ cand, float* __restrict__ cands,
    int N, int ntileM, int ntileN)
{
    // 4 wave regions x 16KB; region: half0 @0 {A 4KB | B 4KB @+4096}, half1 @+8192
    __shared__ __align__(16) unsigned char lds_raw[65536];
    __shared__ float sqi_s[PM];
    __shared__ float sqj_s[PN];
    __shared__ float thr_s[PM];
    __shared__ int   cnt_s[PM];
    __shared__ int   flag_s;                      // ~66.5 KB total -> 2 blocks/CU

    // push buffers alias the (selection-phase-dead) staging LDS
    float (*Bsc)[PBSTRIDE] = (float (*)[PBSTRIDE]) lds_raw;             // 18432 B
    int   (*Bid)[PBSTRIDE] = (int   (*)[PBSTRIDE]) (lds_raw + 32768);   // 18432 B

    const int bid   = blockIdx.x;
    const int q     = bid & 7;
    const int s     = bid >> 3;
    const int ridx  = s / CSPLIT;
    const int split = s - ridx * CSPLIT;
    const int rowb  = q + 8 * ridx;
    if (rowb >= ntileM) return;                   // uniform early exit (pad blocks)
    const int row0  = rowb * PM;

    const int t      = threadIdx.x;
    const int lane   = t & 63;
    const int lane15 = t & 15;
    const int quad   = (t >> 4) & 3;
    const int wave   = t >> 6;
    const int wr     = (wave >> 1) * 64;
    const int wc     = (wave & 1) * 64;
    unsigned char* wreg = lds_raw + (size_t)wave * 16384;
    const int sl     = quad ^ (lane15 & 3);       // swizzled k-granule read slot

    if (t == 0) flag_s = 0;
    if (t < PM) {
        int i = row0 + t;
        sqi_s[t] = (i < N) ? sqf[i] : 0.f;
        thr_s[t] = __builtin_inff();
        cnt_s[t] = 0;
    }

    // register-resident running top-NC list for row (row0 + t), t < PM
    float ls[NC];
    int   li[NC];
#pragma unroll
    for (int m = 0; m < NC; ++m) { ls[m] = __builtin_inff(); li[m] = 0x7fffffff; }

    f32x4 acc[4][4];

    for (int tile = split; tile < ntileN; tile += CSPLIT) {
        int col0 = tile * PN;

        if (t < PN) {
            int j = col0 + t;
            sqj_s[t] = (j < N) ? sqf[j] : __builtin_inff();
        }
        __syncthreads();   // sqj visible + prior selection's Bsc/Bid reads done before re-stage

#pragma unroll
        for (int mt = 0; mt < 4; ++mt)
#pragma unroll
            for (int nt = 0; nt < 4; ++nt)
                acc[mt][nt] = (f32x4){0.f, 0.f, 0.f, 0.f};

        // wave-private DMA of one KB=32 chunk (A 4KB + B 4KB) into half h.
        // 16B-granule source swizzle: LDS slot (r,c) holds global granule c^(r&3).
        auto STAGE = [&](int kc, int h) {
            unsigned char* base = wreg + (size_t)h * 8192;
#pragma unroll
            for (int l = 0; l < 4; ++l) {
                int e = l * 64 + lane;            // 0..255 (16B granules)
                int r = e >> 2;
                int c = (e & 3) ^ (r & 3);
                size_t gA = (size_t)(row0 + wr + r) * DD + kc + c * 8;
                __builtin_amdgcn_global_load_lds(
                    (const unsigned int*)(xnbf + gA),
                    (unsigned int*)(base + (size_t)e * 16), 16, 0, 0);
                size_t gB = (size_t)(col0 + wc + r) * DD + kc + c * 8;
                __builtin_amdgcn_global_load_lds(
                    (const unsigned int*)(xnbf + gB),
                    (unsigned int*)(base + 4096 + (size_t)e * 16), 16, 0, 0);
            }
        };

        STAGE(0, 0);                               // prologue prefetch (8 DMAs in flight)
#pragma unroll 1
        for (int cc = 0; cc < 16; ++cc) {
            if (cc < 15) {
                STAGE((cc + 1) * KB, (cc + 1) & 1);      // prefetch next chunk (16 in flight)
                __builtin_amdgcn_sched_barrier(0);
                asm volatile("s_waitcnt vmcnt(8)" ::: "memory");  // chunk cc landed (wave-local)
            } else {
                __builtin_amdgcn_sched_barrier(0);
                asm volatile("s_waitcnt vmcnt(0)" ::: "memory");
            }
            __builtin_amdgcn_sched_barrier(0);

            const unsigned char* rb = wreg + (size_t)(cc & 1) * 8192;
            bf16x8 af[4], bfg[4];
#pragma unroll
            for (int mt = 0; mt < 4; ++mt)
                af[mt] = *(const bf16x8*)(rb + ((size_t)((mt * 16 + lane15) * 4 + sl)) * 16);
#pragma unroll
            for (int nt = 0; nt < 4; ++nt)
                bfg[nt] = *(const bf16x8*)(rb + 4096 + ((size_t)((nt * 16 + lane15) * 4 + sl)) * 16);
#pragma unroll
            for (int mt = 0; mt < 4; ++mt)
#pragma unroll
                for (int nt = 0; nt < 4; ++nt)
                    acc[mt][nt] = __builtin_amdgcn_mfma_f32_16x16x32_bf16(
                        af[mt], bfg[nt], acc[mt][nt], 0, 0, 0);
            // fence: next iteration's STAGE overwrites half cc&1 -- must not
            // hoist above the MFMAs that consume this half's ds_reads
            __builtin_amdgcn_sched_barrier(0);
        }

        // epilogue: scores in place  s = (sq_i - 2g) + sq_j
#pragma unroll
        for (int mt = 0; mt < 4; ++mt)
#pragma unroll
            for (int nt = 0; nt < 4; ++nt)
#pragma unroll
                for (int reg = 0; reg < 4; ++reg) {
                    int rl = wr + mt * 16 + quad * 4 + reg;
                    int cl = wc + nt * 16 + lane15;
                    float g = acc[mt][nt][reg];
                    acc[mt][nt][reg] = (sqi_s[rl] - 2.f * g) + sqj_s[cl];
                }
        __syncthreads();   // B0: all waves' k-loops done before pushes touch Bsc/Bid alias

        // push/merge rounds (race-free 4-barrier protocol, byte-identical to R5)
        bool tile_edge = (col0 + PN > N);
        unsigned long long done = 0ull;
        for (;;) {
#pragma unroll
            for (int mt = 0; mt < 4; ++mt)
#pragma unroll
                for (int reg = 0; reg < 4; ++reg) {
                    const unsigned long long gb =
                        (0x1111ull << reg) << (mt * 16);
                    int rl = wr + mt * 16 + quad * 4 + reg;
                    float th = thr_s[rl];
                    float gmin = fminf(fminf(acc[mt][0][reg], acc[mt][1][reg]),
                                       fminf(acc[mt][2][reg], acc[mt][3][reg]));
                    if (!tile_edge && gmin > th) { done |= gb; continue; }
                    if ((done & gb) == gb) continue;
#pragma unroll
                    for (int nt = 0; nt < 4; ++nt) {
                        const unsigned long long bit = 1ull << (mt * 16 + nt * 4 + reg);
                        if (!(done & bit)) {
                            float sv = acc[mt][nt][reg];
                            int   j  = col0 + wc + nt * 16 + lane15;
                            if (j < N && sv <= th) {
                                int pos = atomicAdd(&cnt_s[rl], 1);
                                if (pos < PBUF) {
                                    Bsc[rl][pos] = sv;
                                    Bid[rl][pos] = j;
                                    done |= bit;
                                }
                            } else {
                                done |= bit;
                            }
                        }
                    }
                }
            if (done != ~0ull) flag_s = 1;
            __syncthreads();                 // B1
            if (t < PM) {
                int c = cnt_s[t];
                if (c > PBUF) c = PBUF;
                cnt_s[t] = 0;
                for (int m0 = 0; m0 < c; m0 += 4) {
                    float4 s4 = *(const float4*)&Bsc[t][m0];
                    int4   j4 = *(const int4*)&Bid[t][m0];
#pragma unroll
                    for (int e = 0; e < 4; ++e) {
                        if (m0 + e >= c) break;
                        float sv = (e == 0) ? s4.x : (e == 1) ? s4.y : (e == 2) ? s4.z : s4.w;
                        int   j  = (e == 0) ? j4.x : (e == 1) ? j4.y : (e == 2) ? j4.z : j4.w;
                        if (sv < ls[NC - 1] || (sv == ls[NC - 1] && j < li[NC - 1])) {
                            float cs = sv; int cj = j;
#pragma unroll
                            for (int p = 0; p < NC; ++p) {
                                bool lt = (cs < ls[p]) || (cs == ls[p] && cj < li[p]);
                                float ts = ls[p]; int tj = li[p];
                                if (lt) { ls[p] = cs; li[p] = cj; cs = ts; cj = tj; }
                            }
                        }
                    }
                }
                thr_s[t] = ls[NC - 1];
            }
            __syncthreads();                 // B2
            int go = flag_s;
            __syncthreads();                 // B3
            if (t == 0) flag_s = 0;
            __syncthreads();                 // B4
            if (!go) break;
        }
    }
    // write this split's candidates (index + fp32 score) straight from registers
    if (t < PM) {
        int i = row0 + t;
        if (i < N) {
#pragma unroll
            for (int m = 0; m < NC; ++m) {
                cand [(size_t)i * NCTOT + split * NC + m] = li[m];
                cands[(size_t)i * NCTOT + split * NC + m] = ls[m];
            }
        }
    }
}

// ---------------- Kernel D: pruned exact fp64 rescore + top-k ----------------
__global__ __launch_bounds__(256) void rescore_topk(
    const float* __restrict__ x, const double* __restrict__ w,
    const double* __restrict__ sq, const int* __restrict__ cand,
    const float* __restrict__ cands, int* __restrict__ out, int N, int k)
{
    __shared__ float Ssc[4][NCTOT];
    int lane = threadIdx.x & 63;
    int wid  = threadIdx.x >> 6;
    int i = blockIdx.x * 4 + wid;
    if (i >= N) return;

    size_t base = (size_t)i * NCTOT;
    Ssc[wid][lane] = cands[base + lane];
    if (lane < NCTOT - 64) Ssc[wid][64 + lane] = cands[base + 64 + lane];

    // 9th-smallest via pivot counting: pivots cover all 72 slots
    float p0 = Ssc[wid][lane];
    float p1 = Ssc[wid][64 + (lane & 7)];
    int c0 = 0, c1 = 0;
    for (int m = 0; m < NCTOT; ++m) {
        float s = Ssc[wid][m];
        c0 += (s <= p0); c1 += (s <= p1);
    }
    float best = __builtin_inff();
    if (c0 >= k) best = p0;
    if (c1 >= k && p1 < best) best = p1;
#pragma unroll
    for (int off = 32; off > 0; off >>= 1)
        best = fminf(best, __shfl_xor(best, off, 64));
    float cut = best + RS_MARGIN;

    double aw[8];
#pragma unroll
    for (int c = 0; c < 8; ++c) {
        int d = lane + 64 * c;
        aw[c] = (double)x[(size_t)i * DD + d] * w[d];
    }
    double sqi = sq[i];

    double bs[KOUTMAX];
    int    bj[KOUTMAX];
    for (int r = 0; r < k; ++r) { bs[r] = __builtin_inf(); bj[r] = 0x7fffffff; }

    int pend = -1;                    // wave-uniform pending candidate index j
    for (int m = 0; m <= NCTOT; ++m) {
        int j1cand = -1;
        if (m < NCTOT) {
            if (Ssc[wid][m] > cut) continue;          // wave-uniform skip
            j1cand = cand[base + m];
            if (pend < 0) { pend = j1cand; continue; } // buffer first of a pair
        } else if (pend < 0) {
            break;                                     // nothing left
        }
        int j0 = pend, j1 = j1cand;
        pend = -1;
        const float* q0 = &x[(size_t)j0 * DD + lane];
        const float* q1 = (j1 >= 0) ? &x[(size_t)j1 * DD + lane] : q0;
        float v0[8], v1[8];
#pragma unroll
        for (int c = 0; c < 8; ++c) v0[c] = q0[64 * c];
#pragma unroll
        for (int c = 0; c < 8; ++c) v1[c] = q1[64 * c];
        double d0 = 0.0, d1 = 0.0;
#pragma unroll
        for (int c = 0; c < 8; ++c) d0 = fma(aw[c], (double)v0[c], d0);
#pragma unroll
        for (int c = 0; c < 8; ++c) d1 = fma(aw[c], (double)v1[c], d1);
#pragma unroll
        for (int off = 32; off > 0; off >>= 1) {
            d0 += __shfl_xor(d0, off, 64);
            d1 += __shfl_xor(d1, off, 64);
        }
        double s0 = (sqi - 2.0 * d0) + sq[j0];
        double s1 = (j1 >= 0) ? (sqi - 2.0 * d1) + sq[j1] : __builtin_inf();
#pragma unroll 1
        for (int pick = 0; pick < 2; ++pick) {
            double sv = pick ? s1 : s0;
            int    j  = pick ? j1 : j0;
            if (j < 0) continue;
            if (sv < bs[k - 1] || (sv == bs[k - 1] && j < bj[k - 1])) {
                int pos = k - 1;
                while (pos > 0) {
                    double ps = bs[pos - 1]; int pj = bj[pos - 1];
                    if (!(sv < ps || (sv == ps && j < pj))) break;
                    bs[pos] = ps; bj[pos] = pj;
                    --pos;
                }
                bs[pos] = sv; bj[pos] = j;
            }
        }
    }
    if (lane == 0) {
        for (int r = 0; r < k; ++r) {
            out[(size_t)i * k + r]                 = bj[r];
            out[(size_t)N * k + (size_t)i * k + r] = i;
        }
    }
}

extern "C" void kernel_launch(void* const* d_in, const int* in_sizes, int n_in,
                              void* d_out, int out_size, void* d_ws, size_t ws_size,
                              hipStream_t stream) {
    const float* x = (const float*)d_in[0];
    int N = in_sizes[0] / DD;            // 10000
    int k = out_size / (2 * N);          // 9
    if (k > KOUTMAX) k = KOUTMAX;

    char* ws = (char*)d_ws;
    double*         partial = (double*)ws;                       // 400*512*8 = 1638400 B
    double*         rn      = (double*)(ws + 1638400);           // 4096 B
    double*         w       = (double*)(ws + 1642496);           // 4096 B
    double*         sq      = (double*)(ws + 1646592);           // 80000 B
    float*          sqf     = (float*) (ws + 1726592);           // 40000 B
    unsigned short* xnbf    = (unsigned short*)(ws + 1766592);   // N*512*2 = 10.24 MB
    int*            cand    = (int*)   (ws + 12006592);          // N*72*4 = 2.88 MB
    float*          cands   = (float*) (ws + 14886592);          // N*72*4 = 2.88 MB

    int rpb = (N + NBLKA - 1) / NBLKA;
    hipLaunchKernelGGL(colsum_partial, dim3(NBLKA), dim3(256), 0, stream, x, partial, N, rpb);
    hipLaunchKernelGGL(colnorm_finish, dim3(1), dim3(512), 0, stream, partial, rn, w, NBLKA);
    hipLaunchKernelGGL(row_sq, dim3(N), dim3(256), 0, stream, x, rn, sq, sqf, xnbf, N);

    int ntileM = (N + PM - 1) / PM;      // 79
    int ntileN = (N + PN - 1) / PN;      // 79
    int rows_per_xcd = (ntileM + 7) / 8; // 10
    int nblk = 8 * rows_per_xcd * CSPLIT; // 480 (pad blocks exit early)
    hipLaunchKernelGGL(gemm_prefilter, dim3(nblk), dim3(256), 0, stream,
                       xnbf, sqf, cand, cands, N, ntileM, ntileN);

    hipLaunchKernelGGL(rescore_topk, dim3((N + 3) / 4), dim3(256), 0, stream,
                       x, w, sq, cand, cands, (int*)d_out, N, k);
}

// Round 10
// 799.952 us; speedup vs baseline: 1.6324x; 1.0028x over previous
//
#include <hip/hip_runtime.h>
#include <math.h>

#define DD 512
#define NBLKA 400

#define PM 128          // prefilter tile rows
#define PN 128          // prefilter tile cols
#define KB 32           // k-chunk (one MFMA K-step), 16 chunks/tile
#define CSPLIT 6        // column splits -> 480 blocks = ~2/CU, no tail
#define NC 12           // candidates kept per row per split (>= k=9)
#define PBUF 32         // push buffer per row
#define PBSTRIDE 36     // 36 floats -> 144B rows, 16B aligned
#define NCTOT (CSPLIT*NC)   // 72 candidates per row total
#define KOUTMAX 16
#define RS_MARGIN 2e-4f     // rescore prune margin (bf16 score err bound ~3e-5)

typedef __attribute__((ext_vector_type(8))) short bf16x8;   // 8 bf16 = 4 VGPR
typedef __attribute__((ext_vector_type(4))) float f32x4;    // MFMA 16x16 accumulator

static __device__ __forceinline__ unsigned short f2bf(float f) {
    unsigned u = __float_as_uint(f);
    u += 0x7fff + ((u >> 16) & 1);      // round-to-nearest-even
    return (unsigned short)(u >> 16);
}

// ---------------- Kernel A1: partial column sums of x^2 (fp64, deterministic) ----------------
__global__ void colsum_partial(const float* __restrict__ x, double* __restrict__ partial,
                               int N, int rows_per_block) {
    int b = blockIdx.x;
    int t = threadIdx.x;
    int r0 = b * rows_per_block;
    int r1 = min(r0 + rows_per_block, N);
    double s0 = 0.0, s1 = 0.0;
    for (int r = r0; r < r1; ++r) {
        float v0 = x[(size_t)r * DD + t];
        float v1 = x[(size_t)r * DD + t + 256];
        s0 += (double)v0 * (double)v0;
        s1 += (double)v1 * (double)v1;
    }
    partial[(size_t)b * DD + t]       = s0;
    partial[(size_t)b * DD + t + 256] = s1;
}

// ---------------- Kernel A2: rn=1/max(sqrt(s),eps) fp64, w=rn*rn fp64 ----------------
__global__ void colnorm_finish(const double* __restrict__ partial, double* __restrict__ rn,
                               double* __restrict__ w, int nblk) {
    int c = threadIdx.x;                 // 512 threads
    double s = 0.0;
    for (int b = 0; b < nblk; ++b) s += partial[(size_t)b * DD + c];
    double n = fmax(sqrt(s), 1e-12);
    double r = 1.0 / n;
    rn[c]  = r;
    w[c]   = r * r;
}

// ---------------- Kernel B: 1 wave per row, zero barriers (R10 rewrite) ----------------
// Old version: 10000 blocks x 256-thread LDS tree with 9 __syncthreads per
// 512-element row. New: 4 rows/block, 1 wave/row; float4 loads, double2 rn,
// pure shuffle fp64 reduce, ushort4 bf16 stores.
__global__ __launch_bounds__(256) void row_sq(const float* __restrict__ x,
                       const double* __restrict__ rn,
                       double* __restrict__ sq, float* __restrict__ sqf,
                       unsigned short* __restrict__ xnbf, int N) {
    int lane = threadIdx.x & 63;
    int wid  = threadIdx.x >> 6;
    int i = blockIdx.x * 4 + wid;
    if (i >= N) return;

    const float4* xr = (const float4*)(x + (size_t)i * DD);
    float4 v0 = xr[lane];            // elements 4*lane .. +3
    float4 v1 = xr[64 + lane];       // elements 256 + 4*lane .. +3
    const double2* rp = (const double2*)rn;
    double2 r0a = rp[lane * 2],       r0b = rp[lane * 2 + 1];
    double2 r1a = rp[128 + lane * 2], r1b = rp[128 + lane * 2 + 1];

    double a0 = (double)v0.x * r0a.x, a1 = (double)v0.y * r0a.y;
    double a2 = (double)v0.z * r0b.x, a3 = (double)v0.w * r0b.y;
    double b0 = (double)v1.x * r1a.x, b1 = (double)v1.y * r1a.y;
    double b2 = (double)v1.z * r1b.x, b3 = (double)v1.w * r1b.y;

    ushort4 s0 = { f2bf((float)a0), f2bf((float)a1), f2bf((float)a2), f2bf((float)a3) };
    ushort4 s1 = { f2bf((float)b0), f2bf((float)b1), f2bf((float)b2), f2bf((float)b3) };
    *(ushort4*)(xnbf + (size_t)i * DD + lane * 4)       = s0;
    *(ushort4*)(xnbf + (size_t)i * DD + 256 + lane * 4) = s1;

    double loc = a0*a0 + a1*a1 + a2*a2 + a3*a3 + b0*b0 + b1*b1 + b2*b2 + b3*b3;
#pragma unroll
    for (int off = 32; off > 0; off >>= 1)
        loc += __shfl_xor(loc, off, 64);
    if (lane == 0) { sq[i] = loc; sqf[i] = (float)loc; }
}

// ---------------- Kernel C: bf16 MFMA prefilter, 3-DEEP prefetch pipeline ----------------
// R10: cooperative staging (1x DMA traffic) with FOUR 16KB chunk buffers and
// prefetch depth 3. Per chunk: counted s_waitcnt vmcnt(8) (retires exactly
// chunk cc; cc+1,cc+2 stay in flight) -> s_barrier (all waves' chunk-cc DMAs
// landed; all waves done computing cc-1) -> issue STAGE(cc+3) (reuses cc-1's
// buffer -- safe after the barrier) -> compute cc. Latency cover = 3 chunk
// times (~1000 cyc) > HBM latency (~900). R5/R9 covered only 1 chunk
// (~300 cyc) -> each chunk exposed ~400-650 cyc of naked vmcnt stall, the
// prime suspect for the unattributed ~60% (all pipes <30% in R9's counters).
// Selection protocol byte-identical to R5/R9. Granule XOR swizzle kept.
__global__ __launch_bounds__(256, 2) void gemm_prefilter(
    const unsigned short* __restrict__ xnbf,
    const float* __restrict__ sqf, int* __restrict__ cand, float* __restrict__ cands,
    int N, int ntileM, int ntileN)
{
    // 4 chunk buffers x 16KB; buffer b: A @ b*16384 (128 rows x 64B), B @ +8192
    __shared__ __align__(16) unsigned char lds_raw[65536];
    __shared__ float sqi_s[PM];
    __shared__ float sqj_s[PN];
    __shared__ float thr_s[PM];
    __shared__ int   cnt_s[PM];
    __shared__ int   flag_s;                      // ~66.5 KB total -> 2 blocks/CU

    // push buffers alias the (selection-phase-dead) staging LDS
    float (*Bsc)[PBSTRIDE] = (float (*)[PBSTRIDE]) lds_raw;             // 18432 B
    int   (*Bid)[PBSTRIDE] = (int   (*)[PBSTRIDE]) (lds_raw + 32768);   // 18432 B

    const int bid   = blockIdx.x;
    const int q     = bid & 7;
    const int s     = bid >> 3;
    const int ridx  = s / CSPLIT;
    const int split = s - ridx * CSPLIT;
    const int rowb  = q + 8 * ridx;
    if (rowb >= ntileM) return;                   // uniform early exit (pad blocks)
    const int row0  = rowb * PM;

    const int t      = threadIdx.x;
    const int lane15 = t & 15;
    const int quad   = (t >> 4) & 3;
    const int wave   = t >> 6;
    const int wr     = (wave >> 1) * 64;
    const int wc     = (wave & 1) * 64;
    const int sl     = quad ^ (lane15 & 3);       // swizzled k-granule read slot

    if (t == 0) flag_s = 0;
    if (t < PM) {
        int i = row0 + t;
        sqi_s[t] = (i < N) ? sqf[i] : 0.f;
        thr_s[t] = __builtin_inff();
        cnt_s[t] = 0;
    }

    // register-resident running top-NC list for row (row0 + t), t < PM
    float ls[NC];
    int   li[NC];
#pragma unroll
    for (int m = 0; m < NC; ++m) { ls[m] = __builtin_inff(); li[m] = 0x7fffffff; }

    f32x4 acc[4][4];

    for (int tile = split; tile < ntileN; tile += CSPLIT) {
        int col0 = tile * PN;

        if (t < PN) {
            int j = col0 + t;
            sqj_s[t] = (j < N) ? sqf[j] : __builtin_inff();
        }
        __syncthreads();   // sqj visible + prior selection's Bsc/Bid accesses done

#pragma unroll
        for (int mt = 0; mt < 4; ++mt)
#pragma unroll
            for (int nt = 0; nt < 4; ++nt)
                acc[mt][nt] = (f32x4){0.f, 0.f, 0.f, 0.f};

        // cooperative DMA of one KB=32 chunk (A 8KB + B 8KB) into buffer buf.
        // 4 DMA instrs/thread (16 vmcnt units/chunk... 4 per thread).
        // 16B-granule source swizzle: LDS slot (row,c) holds granule c^(row&3).
        auto STAGE = [&](int kc, int buf) {
#pragma unroll
            for (int l = 0; l < 4; ++l) {
                int e      = t + l * 256;         // 0..1023 (16B granules)
                int region = e >> 9;              // 0=A, 1=B
                int re     = e & 511;
                int row    = re >> 2;
                int c      = (re & 3) ^ (row & 3);
                int basei  = region ? col0 : row0;
                size_t g = (size_t)(basei + row) * DD + kc + c * 8;
                __builtin_amdgcn_global_load_lds(
                    (const unsigned int*)(xnbf + g),
                    (unsigned int*)(lds_raw + (size_t)buf * 16384 + (size_t)e * 16), 16, 0, 0);
            }
        };

        STAGE(0, 0); STAGE(KB, 1); STAGE(2 * KB, 2);   // 3-deep prologue (12 DMAs/thread... 12 vmcnt units)
#pragma unroll 1
        for (int cc = 0; cc < 16; ++cc) {
            // outstanding at top: chunks cc..min(cc+2,15) = 12/8/4 units
            if (cc <= 13)      asm volatile("s_waitcnt vmcnt(8)" ::: "memory");
            else if (cc == 14) asm volatile("s_waitcnt vmcnt(4)" ::: "memory");
            else               asm volatile("s_waitcnt vmcnt(0)" ::: "memory");
            __builtin_amdgcn_s_barrier();      // chunk cc staged by ALL waves; all done cc-1
            __builtin_amdgcn_sched_barrier(0);
            if (cc + 3 < 16)
                STAGE((cc + 3) * KB, (cc + 3) & 3);    // reuses chunk cc-1's buffer
            __builtin_amdgcn_sched_barrier(0);

            const unsigned char* rb = lds_raw + (size_t)(cc & 3) * 16384;
            bf16x8 af[4], bfg[4];
#pragma unroll
            for (int mt = 0; mt < 4; ++mt)
                af[mt] = *(const bf16x8*)(rb + (size_t)(wr + mt * 16 + lane15) * 64 + sl * 16);
#pragma unroll
            for (int nt = 0; nt < 4; ++nt)
                bfg[nt] = *(const bf16x8*)(rb + 8192 + (size_t)(wc + nt * 16 + lane15) * 64 + sl * 16);
#pragma unroll
            for (int mt = 0; mt < 4; ++mt)
#pragma unroll
                for (int nt = 0; nt < 4; ++nt)
                    acc[mt][nt] = __builtin_amdgcn_mfma_f32_16x16x32_bf16(
                        af[mt], bfg[nt], acc[mt][nt], 0, 0, 0);
            __builtin_amdgcn_sched_barrier(0);
        }

        // epilogue: scores in place  s = (sq_i - 2g) + sq_j
#pragma unroll
        for (int mt = 0; mt < 4; ++mt)
#pragma unroll
            for (int nt = 0; nt < 4; ++nt)
#pragma unroll
                for (int reg = 0; reg < 4; ++reg) {
                    int rl = wr + mt * 16 + quad * 4 + reg;
                    int cl = wc + nt * 16 + lane15;
                    float g = acc[mt][nt][reg];
                    acc[mt][nt][reg] = (sqi_s[rl] - 2.f * g) + sqj_s[cl];
                }
        __syncthreads();   // B0: all waves' k-loops done before pushes touch the alias

        // push/merge rounds (race-free 4-barrier protocol, byte-identical to R5)
        bool tile_edge = (col0 + PN > N);
        unsigned long long done = 0ull;
        for (;;) {
#pragma unroll
            for (int mt = 0; mt < 4; ++mt)
#pragma unroll
                for (int reg = 0; reg < 4; ++reg) {
                    const unsigned long long gb =
                        (0x1111ull << reg) << (mt * 16);
                    int rl = wr + mt * 16 + quad * 4 + reg;
                    float th = thr_s[rl];
                    float gmin = fminf(fminf(acc[mt][0][reg], acc[mt][1][reg]),
                                       fminf(acc[mt][2][reg], acc[mt][3][reg]));
                    if (!tile_edge && gmin > th) { done |= gb; continue; }
                    if ((done & gb) == gb) continue;
#pragma unroll
                    for (int nt = 0; nt < 4; ++nt) {
                        const unsigned long long bit = 1ull << (mt * 16 + nt * 4 + reg);
                        if (!(done & bit)) {
                            float sv = acc[mt][nt][reg];
                            int   j  = col0 + wc + nt * 16 + lane15;
                            if (j < N && sv <= th) {
                                int pos = atomicAdd(&cnt_s[rl], 1);
                                if (pos < PBUF) {
                                    Bsc[rl][pos] = sv;
                                    Bid[rl][pos] = j;
                                    done |= bit;
                                }
                            } else {
                                done |= bit;
                            }
                        }
                    }
                }
            if (done != ~0ull) flag_s = 1;
            __syncthreads();                 // B1
            if (t < PM) {
                int c = cnt_s[t];
                if (c > PBUF) c = PBUF;
                cnt_s[t] = 0;
                for (int m0 = 0; m0 < c; m0 += 4) {
                    float4 s4 = *(const float4*)&Bsc[t][m0];
                    int4   j4 = *(const int4*)&Bid[t][m0];
#pragma unroll
                    for (int e = 0; e < 4; ++e) {
                        if (m0 + e >= c) break;
                        float sv = (e == 0) ? s4.x : (e == 1) ? s4.y : (e == 2) ? s4.z : s4.w;
                        int   j  = (e == 0) ? j4.x : (e == 1) ? j4.y : (e == 2) ? j4.z : j4.w;
                        if (sv < ls[NC - 1] || (sv == ls[NC - 1] && j < li[NC - 1])) {
                            float cs = sv; int cj = j;
#pragma unroll
                            for (int p = 0; p < NC; ++p) {
                                bool lt = (cs < ls[p]) || (cs == ls[p] && cj < li[p]);
                                float ts = ls[p]; int tj = li[p];
                                if (lt) { ls[p] = cs; li[p] = cj; cs = ts; cj = tj; }
                            }
                        }
                    }
                }
                thr_s[t] = ls[NC - 1];
            }
            __syncthreads();                 // B2
            int go = flag_s;
            __syncthreads();                 // B3
            if (t == 0) flag_s = 0;
            __syncthreads();                 // B4
            if (!go) break;
        }
    }
    // write this split's candidates (index + fp32 score) straight from registers
    if (t < PM) {
        int i = row0 + t;
        if (i < N) {
#pragma unroll
            for (int m = 0; m < NC; ++m) {
                cand [(size_t)i * NCTOT + split * NC + m] = li[m];
                cands[(size_t)i * NCTOT + split * NC + m] = ls[m];
            }
        }
    }
}

// ---------------- Kernel D: pruned exact fp64 rescore + top-k ----------------
__global__ __launch_bounds__(256) void rescore_topk(
    const float* __restrict__ x, const double* __restrict__ w,
    const double* __restrict__ sq, const int* __restrict__ cand,
    const float* __restrict__ cands, int* __restrict__ out, int N, int k)
{
    __shared__ float Ssc[4][NCTOT];
    int lane = threadIdx.x & 63;
    int wid  = threadIdx.x >> 6;
    int i = blockIdx.x * 4 + wid;
    if (i >= N) return;

    size_t base = (size_t)i * NCTOT;
    Ssc[wid][lane] = cands[base + lane];
    if (lane < NCTOT - 64) Ssc[wid][64 + lane] = cands[base + 64 + lane];

    // 9th-smallest via pivot counting: pivots cover all 72 slots
    float p0 = Ssc[wid][lane];
    float p1 = Ssc[wid][64 + (lane & 7)];
    int c0 = 0, c1 = 0;
    for (int m = 0; m < NCTOT; ++m) {
        float s = Ssc[wid][m];
        c0 += (s <= p0); c1 += (s <= p1);
    }
    float best = __builtin_inff();
    if (c0 >= k) best = p0;
    if (c1 >= k && p1 < best) best = p1;
#pragma unroll
    for (int off = 32; off > 0; off >>= 1)
        best = fminf(best, __shfl_xor(best, off, 64));
    float cut = best + RS_MARGIN;

    double aw[8];
#pragma unroll
    for (int c = 0; c < 8; ++c) {
        int d = lane + 64 * c;
        aw[c] = (double)x[(size_t)i * DD + d] * w[d];
    }
    double sqi = sq[i];

    double bs[KOUTMAX];
    int    bj[KOUTMAX];
    for (int r = 0; r < k; ++r) { bs[r] = __builtin_inf(); bj[r] = 0x7fffffff; }

    int pend = -1;                    // wave-uniform pending candidate index j
    for (int m = 0; m <= NCTOT; ++m) {
        int j1cand = -1;
        if (m < NCTOT) {
            if (Ssc[wid][m] > cut) continue;          // wave-uniform skip
            j1cand = cand[base + m];
            if (pend < 0) { pend = j1cand; continue; } // buffer first of a pair
        } else if (pend < 0) {
            break;                                     // nothing left
        }
        int j0 = pend, j1 = j1cand;
        pend = -1;
        const float* q0 = &x[(size_t)j0 * DD + lane];
        const float* q1 = (j1 >= 0) ? &x[(size_t)j1 * DD + lane] : q0;
        float v0[8], v1[8];
#pragma unroll
        for (int c = 0; c < 8; ++c) v0[c] = q0[64 * c];
#pragma unroll
        for (int c = 0; c < 8; ++c) v1[c] = q1[64 * c];
        double d0 = 0.0, d1 = 0.0;
#pragma unroll
        for (int c = 0; c < 8; ++c) d0 = fma(aw[c], (double)v0[c], d0);
#pragma unroll
        for (int c = 0; c < 8; ++c) d1 = fma(aw[c], (double)v1[c], d1);
#pragma unroll
        for (int off = 32; off > 0; off >>= 1) {
            d0 += __shfl_xor(d0, off, 64);
            d1 += __shfl_xor(d1, off, 64);
        }
        double s0 = (sqi - 2.0 * d0) + sq[j0];
        double s1 = (j1 >= 0) ? (sqi - 2.0 * d1) + sq[j1] : __builtin_inf();
#pragma unroll 1
        for (int pick = 0; pick < 2; ++pick) {
            double sv = pick ? s1 : s0;
            int    j  = pick ? j1 : j0;
            if (j < 0) continue;
            if (sv < bs[k - 1] || (sv == bs[k - 1] && j < bj[k - 1])) {
                int pos = k - 1;
                while (pos > 0) {
                    double ps = bs[pos - 1]; int pj = bj[pos - 1];
                    if (!(sv < ps || (sv == ps && j < pj))) break;
                    bs[pos] = ps; bj[pos] = pj;
                    --pos;
                }
                bs[pos] = sv; bj[pos] = j;
            }
        }
    }
    if (lane == 0) {
        for (int r = 0; r < k; ++r) {
            out[(size_t)i * k + r]                 = bj[r];
            out[(size_t)N * k + (size_t)i * k + r] = i;
        }
    }
}

extern "C" void kernel_launch(void* const* d_in, const int* in_sizes, int n_in,
                              void* d_out, int out_size, void* d_ws, size_t ws_size,
                              hipStream_t stream) {
    const float* x = (const float*)d_in[0];
    int N = in_sizes[0] / DD;            // 10000
    int k = out_size / (2 * N);          // 9
    if (k > KOUTMAX) k = KOUTMAX;

    char* ws = (char*)d_ws;
    double*         partial = (double*)ws;                       // 400*512*8 = 1638400 B
    double*         rn      = (double*)(ws + 1638400);           // 4096 B
    double*         w       = (double*)(ws + 1642496);           // 4096 B
    double*         sq      = (double*)(ws + 1646592);           // 80000 B
    float*          sqf     = (float*) (ws + 1726592);           // 40000 B
    unsigned short* xnbf    = (unsigned short*)(ws + 1766592);   // N*512*2 = 10.24 MB
    int*            cand    = (int*)   (ws + 12006592);          // N*72*4 = 2.88 MB
    float*          cands   = (float*) (ws + 14886592);          // N*72*4 = 2.88 MB

    int rpb = (N + NBLKA - 1) / NBLKA;
    hipLaunchKernelGGL(colsum_partial, dim3(NBLKA), dim3(256), 0, stream, x, partial, N, rpb);
    hipLaunchKernelGGL(colnorm_finish, dim3(1), dim3(512), 0, stream, partial, rn, w, NBLKA);
    hipLaunchKernelGGL(row_sq, dim3((N + 3) / 4), dim3(256), 0, stream, x, rn, sq, sqf, xnbf, N);

    int ntileM = (N + PM - 1) / PM;      // 79
    int ntileN = (N + PN - 1) / PN;      // 79
    int rows_per_xcd = (ntileM + 7) / 8; // 10
    int nblk = 8 * rows_per_xcd * CSPLIT; // 480 (pad blocks exit early)
    hipLaunchKernelGGL(gemm_prefilter, dim3(nblk), dim3(256), 0, stream,
                       xnbf, sqf, cand, cands, N, ntileM, ntileN);

    hipLaunchKernelGGL(rescore_topk, dim3((N + 3) / 4), dim3(256), 0, stream,
                       x, w, sq, cand, cands, (int*)d_out, N, k);
}

// Round 11
// 706.333 us; speedup vs baseline: 1.8487x; 1.1325x over previous
//
#include <hip/hip_runtime.h>
#include <math.h>

#define DD 512
#define NBLKA 400

#define PM 128          // prefilter tile rows
#define PN 256          // prefilter tile cols (R11: doubled -> half the passes)
#define KB 32           // k-chunk (one MFMA K-step), 16 chunks/tile
#define CSPLIT 6        // column splits of 40 col-tiles -> 480 blocks = 2/CU
#define NC 12           // candidates kept per row per split (>= k=9)
#define PBUF 32         // push buffer per row
#define PBSTRIDE 36     // 36 floats -> 144B rows, 16B aligned
#define NCTOT (CSPLIT*NC)   // 72 candidates per row total
#define KOUTMAX 16
#define RS_MARGIN 2e-4f     // rescore prune margin (bf16 score err bound ~3e-5)

typedef __attribute__((ext_vector_type(8))) short bf16x8;   // 8 bf16 = 4 VGPR
typedef __attribute__((ext_vector_type(4))) float f32x4;    // MFMA 16x16 accumulator

static __device__ __forceinline__ unsigned short f2bf(float f) {
    unsigned u = __float_as_uint(f);
    u += 0x7fff + ((u >> 16) & 1);      // round-to-nearest-even
    return (unsigned short)(u >> 16);
}

// ---------------- Kernel A1: partial column sums of x^2 (fp64, deterministic) ----------------
__global__ void colsum_partial(const float* __restrict__ x, double* __restrict__ partial,
                               int N, int rows_per_block) {
    int b = blockIdx.x;
    int t = threadIdx.x;
    int r0 = b * rows_per_block;
    int r1 = min(r0 + rows_per_block, N);
    double s0 = 0.0, s1 = 0.0;
    for (int r = r0; r < r1; ++r) {
        float v0 = x[(size_t)r * DD + t];
        float v1 = x[(size_t)r * DD + t + 256];
        s0 += (double)v0 * (double)v0;
        s1 += (double)v1 * (double)v1;
    }
    partial[(size_t)b * DD + t]       = s0;
    partial[(size_t)b * DD + t + 256] = s1;
}

// ---------------- Kernel A2: rn=1/max(sqrt(s),eps) fp64, w=rn*rn fp64 ----------------
__global__ void colnorm_finish(const double* __restrict__ partial, double* __restrict__ rn,
                               double* __restrict__ w, int nblk) {
    int c = threadIdx.x;                 // 512 threads
    double s = 0.0;
    for (int b = 0; b < nblk; ++b) s += partial[(size_t)b * DD + c];
    double n = fmax(sqrt(s), 1e-12);
    double r = 1.0 / n;
    rn[c]  = r;
    w[c]   = r * r;
}

// ---------------- Kernel B: 1 wave per row, zero barriers ----------------
__global__ __launch_bounds__(256) void row_sq(const float* __restrict__ x,
                       const double* __restrict__ rn,
                       double* __restrict__ sq, float* __restrict__ sqf,
                       unsigned short* __restrict__ xnbf, int N) {
    int lane = threadIdx.x & 63;
    int wid  = threadIdx.x >> 6;
    int i = blockIdx.x * 4 + wid;
    if (i >= N) return;

    const float4* xr = (const float4*)(x + (size_t)i * DD);
    float4 v0 = xr[lane];            // elements 4*lane .. +3
    float4 v1 = xr[64 + lane];       // elements 256 + 4*lane .. +3
    const double2* rp = (const double2*)rn;
    double2 r0a = rp[lane * 2],       r0b = rp[lane * 2 + 1];
    double2 r1a = rp[128 + lane * 2], r1b = rp[128 + lane * 2 + 1];

    double a0 = (double)v0.x * r0a.x, a1 = (double)v0.y * r0a.y;
    double a2 = (double)v0.z * r0b.x, a3 = (double)v0.w * r0b.y;
    double b0 = (double)v1.x * r1a.x, b1 = (double)v1.y * r1a.y;
    double b2 = (double)v1.z * r1b.x, b3 = (double)v1.w * r1b.y;

    ushort4 s0 = { f2bf((float)a0), f2bf((float)a1), f2bf((float)a2), f2bf((float)a3) };
    ushort4 s1 = { f2bf((float)b0), f2bf((float)b1), f2bf((float)b2), f2bf((float)b3) };
    *(ushort4*)(xnbf + (size_t)i * DD + lane * 4)       = s0;
    *(ushort4*)(xnbf + (size_t)i * DD + 256 + lane * 4) = s1;

    double loc = a0*a0 + a1*a1 + a2*a2 + a3*a3 + b0*b0 + b1*b1 + b2*b2 + b3*b3;
#pragma unroll
    for (int off = 32; off > 0; off >>= 1)
        loc += __shfl_xor(loc, off, 64);
    if (lane == 0) { sq[i] = loc; sqf[i] = (float)loc; }
}

// ---------------- Kernel C: bf16 MFMA prefilter, 128x256 tile ----------------
// R11: every micro-variant of the 128x128 structure (barriers removed R9,
// 3-deep prefetch R10, occupancy R3, swizzle R7) measured the same ~430-460us
// -> the cost is the per-chunk/per-pass cadence itself (beats x latency no
// co-resident wave covers). This round halves the number of beats per block:
// PN=256 (acc 4x8 = 128 VGPR/wave, 2x2 wave grid, each wave owns 64x128),
// column passes per block 13.2 -> ~6.7, A-staging traffic halved. K-loop is
// the proven R5 scheme (2 buffers, counted vmcnt; 6 DMA/thread/chunk ->
// steady-state wait vmcnt(6)). Selection protocol identical, extended to
// 8 nt-groups via two 64-bit done masks. ~51.7KB LDS -> 2 blocks/CU.
__global__ __launch_bounds__(256, 2) void gemm_prefilter(
    const unsigned short* __restrict__ xnbf,
    const float* __restrict__ sqf, int* __restrict__ cand, float* __restrict__ cands,
    int N, int ntileM, int ntileN)
{
    // 2 chunk buffers x 24KB: buffer b @ b*24576 {A 8KB (128r x 64B) | B 16KB @ +8192 (256r x 64B)}
    __shared__ __align__(16) unsigned char lds_raw[49152];
    __shared__ float sqi_s[PM];
    __shared__ float sqj_s[PN];
    __shared__ float thr_s[PM];
    __shared__ int   cnt_s[PM];
    __shared__ int   flag_s;                      // ~51.7 KB total -> 2 blocks/CU

    // push buffers alias the (selection-phase-dead) staging LDS
    float (*Bsc)[PBSTRIDE] = (float (*)[PBSTRIDE]) lds_raw;             // 18432 B in buf0
    int   (*Bid)[PBSTRIDE] = (int   (*)[PBSTRIDE]) (lds_raw + 24576);   // 18432 B in buf1

    const int bid   = blockIdx.x;
    const int q     = bid & 7;
    const int s     = bid >> 3;
    const int ridx  = s / CSPLIT;
    const int split = s - ridx * CSPLIT;
    const int rowb  = q + 8 * ridx;
    if (rowb >= ntileM) return;                   // uniform early exit (pad blocks)
    const int row0  = rowb * PM;

    const int t      = threadIdx.x;
    const int lane15 = t & 15;
    const int quad   = (t >> 4) & 3;
    const int wave   = t >> 6;
    const int wr     = (wave >> 1) * 64;          // row half (0/64)
    const int wc     = (wave & 1) * 128;          // col half (0/128)
    const int sl     = quad ^ (lane15 & 3);       // swizzled k-granule read slot

    if (t == 0) flag_s = 0;
    if (t < PM) {
        int i = row0 + t;
        sqi_s[t] = (i < N) ? sqf[i] : 0.f;
        thr_s[t] = __builtin_inff();
        cnt_s[t] = 0;
    }

    // register-resident running top-NC list for row (row0 + t), t < PM
    float ls[NC];
    int   li[NC];
#pragma unroll
    for (int m = 0; m < NC; ++m) { ls[m] = __builtin_inff(); li[m] = 0x7fffffff; }

    f32x4 acc[4][8];                              // [mt][nt] -- 128 VGPRs

    for (int tile = split; tile < ntileN; tile += CSPLIT) {
        int col0 = tile * PN;

        {   // sqj fill: all 256 threads cover the 256 columns
            int j = col0 + t;
            sqj_s[t] = (j < N) ? sqf[j] : __builtin_inff();
        }
        __syncthreads();   // sqj visible + prior selection's Bsc/Bid accesses done

#pragma unroll
        for (int mt = 0; mt < 4; ++mt)
#pragma unroll
            for (int nt = 0; nt < 8; ++nt)
                acc[mt][nt] = (f32x4){0.f, 0.f, 0.f, 0.f};

        // cooperative DMA of one KB=32 chunk: A 512 granules + B 1024 granules
        // = 6 DMA instrs/thread. 16B-granule XOR swizzle c^=(row&3).
        auto STAGE = [&](int kc, int buf) {
            unsigned char* base = lds_raw + (size_t)buf * 24576;
#pragma unroll
            for (int l = 0; l < 2; ++l) {         // A region: 512 granules
                int e   = t + l * 256;
                int row = e >> 2;
                int c   = (e & 3) ^ (row & 3);
                size_t g = (size_t)(row0 + row) * DD + kc + c * 8;
                __builtin_amdgcn_global_load_lds(
                    (const unsigned int*)(xnbf + g),
                    (unsigned int*)(base + (size_t)e * 16), 16, 0, 0);
            }
#pragma unroll
            for (int l = 0; l < 4; ++l) {         // B region: 1024 granules
                int e   = t + l * 256;
                int row = e >> 2;
                int c   = (e & 3) ^ (row & 3);
                size_t g = (size_t)(col0 + row) * DD + kc + c * 8;
                __builtin_amdgcn_global_load_lds(
                    (const unsigned int*)(xnbf + g),
                    (unsigned int*)(base + 8192 + (size_t)e * 16), 16, 0, 0);
            }
        };

        STAGE(0, 0);                               // prologue prefetch (6 units)
#pragma unroll 1
        for (int cc = 0; cc < 16; ++cc) {
            if (cc < 15) {
                STAGE((cc + 1) * KB, (cc + 1) & 1);      // +6 -> 12 outstanding
                __builtin_amdgcn_sched_barrier(0);
                asm volatile("s_waitcnt vmcnt(6)" ::: "memory");  // retire chunk cc
            } else {
                __builtin_amdgcn_sched_barrier(0);
                asm volatile("s_waitcnt vmcnt(0)" ::: "memory");
            }
            __builtin_amdgcn_s_barrier();          // all waves' chunk-cc parts landed
            __builtin_amdgcn_sched_barrier(0);

            const unsigned char* rb = lds_raw + (size_t)(cc & 1) * 24576;
            bf16x8 af[4], bfg[8];
#pragma unroll
            for (int mt = 0; mt < 4; ++mt)
                af[mt] = *(const bf16x8*)(rb + (size_t)(wr + mt * 16 + lane15) * 64 + sl * 16);
#pragma unroll
            for (int nt = 0; nt < 8; ++nt)
                bfg[nt] = *(const bf16x8*)(rb + 8192 + (size_t)(wc + nt * 16 + lane15) * 64 + sl * 16);
#pragma unroll
            for (int mt = 0; mt < 4; ++mt)
#pragma unroll
                for (int nt = 0; nt < 8; ++nt)
                    acc[mt][nt] = __builtin_amdgcn_mfma_f32_16x16x32_bf16(
                        af[mt], bfg[nt], acc[mt][nt], 0, 0, 0);
            __builtin_amdgcn_sched_barrier(0);
            __builtin_amdgcn_s_barrier();          // reads done before buf re-staged
        }

        // epilogue: scores in place  s = (sq_i - 2g) + sq_j
#pragma unroll
        for (int mt = 0; mt < 4; ++mt)
#pragma unroll
            for (int nt = 0; nt < 8; ++nt)
#pragma unroll
                for (int reg = 0; reg < 4; ++reg) {
                    int rl = wr + mt * 16 + quad * 4 + reg;
                    int cl = wc + nt * 16 + lane15;
                    float g = acc[mt][nt][reg];
                    acc[mt][nt][reg] = (sqi_s[rl] - 2.f * g) + sqj_s[cl];
                }
        __syncthreads();   // all k-loops done before pushes touch the alias

        // push/merge rounds: R5 protocol, two 64-bit done masks (nt halves)
        bool tile_edge = (col0 + PN > N);
        unsigned long long done0 = 0ull, done1 = 0ull;
        for (;;) {
#pragma unroll
            for (int hn = 0; hn < 2; ++hn) {
#pragma unroll
                for (int mt = 0; mt < 4; ++mt)
#pragma unroll
                    for (int reg = 0; reg < 4; ++reg) {
                        const unsigned long long gb =
                            (0x1111ull << reg) << (mt * 16);
                        unsigned long long dn = hn ? done1 : done0;
                        int rl = wr + mt * 16 + quad * 4 + reg;
                        float th = thr_s[rl];
                        float gmin = fminf(
                            fminf(acc[mt][hn * 4 + 0][reg], acc[mt][hn * 4 + 1][reg]),
                            fminf(acc[mt][hn * 4 + 2][reg], acc[mt][hn * 4 + 3][reg]));
                        if (!tile_edge && gmin > th) {
                            if (hn) done1 |= gb; else done0 |= gb;
                            continue;
                        }
                        if ((dn & gb) == gb) continue;
#pragma unroll
                        for (int u = 0; u < 4; ++u) {
                            const unsigned long long bit = 1ull << (mt * 16 + u * 4 + reg);
                            if (!(dn & bit)) {
                                float sv = acc[mt][hn * 4 + u][reg];
                                int   j  = col0 + wc + (hn * 4 + u) * 16 + lane15;
                                bool ok = false;
                                if (j < N && sv <= th) {
                                    int pos = atomicAdd(&cnt_s[rl], 1);
                                    if (pos < PBUF) {
                                        Bsc[rl][pos] = sv;
                                        Bid[rl][pos] = j;
                                        ok = true;
                                    }
                                } else {
                                    ok = true;
                                }
                                if (ok) { if (hn) done1 |= bit; else done0 |= bit; }
                            }
                        }
                    }
            }
            if (done0 != ~0ull || done1 != ~0ull) flag_s = 1;
            __syncthreads();                 // B1
            if (t < PM) {
                int c = cnt_s[t];
                if (c > PBUF) c = PBUF;
                cnt_s[t] = 0;
                for (int m0 = 0; m0 < c; m0 += 4) {
                    float4 s4 = *(const float4*)&Bsc[t][m0];
                    int4   j4 = *(const int4*)&Bid[t][m0];
#pragma unroll
                    for (int e = 0; e < 4; ++e) {
                        if (m0 + e >= c) break;
                        float sv = (e == 0) ? s4.x : (e == 1) ? s4.y : (e == 2) ? s4.z : s4.w;
                        int   j  = (e == 0) ? j4.x : (e == 1) ? j4.y : (e == 2) ? j4.z : j4.w;
                        if (sv < ls[NC - 1] || (sv == ls[NC - 1] && j < li[NC - 1])) {
                            float cs = sv; int cj = j;
#pragma unroll
                            for (int p = 0; p < NC; ++p) {
                                bool lt = (cs < ls[p]) || (cs == ls[p] && cj < li[p]);
                                float ts = ls[p]; int tj = li[p];
                                if (lt) { ls[p] = cs; li[p] = cj; cs = ts; cj = tj; }
                            }
                        }
                    }
                }
                thr_s[t] = ls[NC - 1];
            }
            __syncthreads();                 // B2
            int go = flag_s;
            __syncthreads();                 // B3
            if (t == 0) flag_s = 0;
            __syncthreads();                 // B4
            if (!go) break;
        }
    }
    // write this split's candidates (index + fp32 score) straight from registers
    if (t < PM) {
        int i = row0 + t;
        if (i < N) {
#pragma unroll
            for (int m = 0; m < NC; ++m) {
                cand [(size_t)i * NCTOT + split * NC + m] = li[m];
                cands[(size_t)i * NCTOT + split * NC + m] = ls[m];
            }
        }
    }
}

// ---------------- Kernel D: pruned exact fp64 rescore + top-k ----------------
__global__ __launch_bounds__(256) void rescore_topk(
    const float* __restrict__ x, const double* __restrict__ w,
    const double* __restrict__ sq, const int* __restrict__ cand,
    const float* __restrict__ cands, int* __restrict__ out, int N, int k)
{
    __shared__ float Ssc[4][NCTOT];
    int lane = threadIdx.x & 63;
    int wid  = threadIdx.x >> 6;
    int i = blockIdx.x * 4 + wid;
    if (i >= N) return;

    size_t base = (size_t)i * NCTOT;
    Ssc[wid][lane] = cands[base + lane];
    if (lane < NCTOT - 64) Ssc[wid][64 + lane] = cands[base + 64 + lane];

    // 9th-smallest via pivot counting: pivots cover all 72 slots
    float p0 = Ssc[wid][lane];
    float p1 = Ssc[wid][64 + (lane & 7)];
    int c0 = 0, c1 = 0;
    for (int m = 0; m < NCTOT; ++m) {
        float s = Ssc[wid][m];
        c0 += (s <= p0); c1 += (s <= p1);
    }
    float best = __builtin_inff();
    if (c0 >= k) best = p0;
    if (c1 >= k && p1 < best) best = p1;
#pragma unroll
    for (int off = 32; off > 0; off >>= 1)
        best = fminf(best, __shfl_xor(best, off, 64));
    float cut = best + RS_MARGIN;

    double aw[8];
#pragma unroll
    for (int c = 0; c < 8; ++c) {
        int d = lane + 64 * c;
        aw[c] = (double)x[(size_t)i * DD + d] * w[d];
    }
    double sqi = sq[i];

    double bs[KOUTMAX];
    int    bj[KOUTMAX];
    for (int r = 0; r < k; ++r) { bs[r] = __builtin_inf(); bj[r] = 0x7fffffff; }

    int pend = -1;                    // wave-uniform pending candidate index j
    for (int m = 0; m <= NCTOT; ++m) {
        int j1cand = -1;
        if (m < NCTOT) {
            if (Ssc[wid][m] > cut) continue;          // wave-uniform skip
            j1cand = cand[base + m];
            if (pend < 0) { pend = j1cand; continue; } // buffer first of a pair
        } else if (pend < 0) {
            break;                                     // nothing left
        }
        int j0 = pend, j1 = j1cand;
        pend = -1;
        const float* q0 = &x[(size_t)j0 * DD + lane];
        const float* q1 = (j1 >= 0) ? &x[(size_t)j1 * DD + lane] : q0;
        float v0[8], v1[8];
#pragma unroll
        for (int c = 0; c < 8; ++c) v0[c] = q0[64 * c];
#pragma unroll
        for (int c = 0; c < 8; ++c) v1[c] = q1[64 * c];
        double d0 = 0.0, d1 = 0.0;
#pragma unroll
        for (int c = 0; c < 8; ++c) d0 = fma(aw[c], (double)v0[c], d0);
#pragma unroll
        for (int c = 0; c < 8; ++c) d1 = fma(aw[c], (double)v1[c], d1);
#pragma unroll
        for (int off = 32; off > 0; off >>= 1) {
            d0 += __shfl_xor(d0, off, 64);
            d1 += __shfl_xor(d1, off, 64);
        }
        double s0 = (sqi - 2.0 * d0) + sq[j0];
        double s1 = (j1 >= 0) ? (sqi - 2.0 * d1) + sq[j1] : __builtin_inf();
#pragma unroll 1
        for (int pick = 0; pick < 2; ++pick) {
            double sv = pick ? s1 : s0;
            int    j  = pick ? j1 : j0;
            if (j < 0) continue;
            if (sv < bs[k - 1] || (sv == bs[k - 1] && j < bj[k - 1])) {
                int pos = k - 1;
                while (pos > 0) {
                    double ps = bs[pos - 1]; int pj = bj[pos - 1];
                    if (!(sv < ps || (sv == ps && j < pj))) break;
                    bs[pos] = ps; bj[pos] = pj;
                    --pos;
                }
                bs[pos] = sv; bj[pos] = j;
            }
        }
    }
    if (lane == 0) {
        for (int r = 0; r < k; ++r) {
            out[(size_t)i * k + r]                 = bj[r];
            out[(size_t)N * k + (size_t)i * k + r] = i;
        }
    }
}

extern "C" void kernel_launch(void* const* d_in, const int* in_sizes, int n_in,
                              void* d_out, int out_size, void* d_ws, size_t ws_size,
                              hipStream_t stream) {
    const float* x = (const float*)d_in[0];
    int N = in_sizes[0] / DD;            // 10000
    int k = out_size / (2 * N);          // 9
    if (k > KOUTMAX) k = KOUTMAX;

    char* ws = (char*)d_ws;
    double*         partial = (double*)ws;                       // 400*512*8 = 1638400 B
    double*         rn      = (double*)(ws + 1638400);           // 4096 B
    double*         w       = (double*)(ws + 1642496);           // 4096 B
    double*         sq      = (double*)(ws + 1646592);           // 80000 B
    float*          sqf     = (float*) (ws + 1726592);           // 40000 B
    unsigned short* xnbf    = (unsigned short*)(ws + 1766592);   // N*512*2 = 10.24 MB
    int*            cand    = (int*)   (ws + 12006592);          // N*72*4 = 2.88 MB
    float*          cands   = (float*) (ws + 14886592);          // N*72*4 = 2.88 MB

    int rpb = (N + NBLKA - 1) / NBLKA;
    hipLaunchKernelGGL(colsum_partial, dim3(NBLKA), dim3(256), 0, stream, x, partial, N, rpb);
    hipLaunchKernelGGL(colnorm_finish, dim3(1), dim3(512), 0, stream, partial, rn, w, NBLKA);
    hipLaunchKernelGGL(row_sq, dim3((N + 3) / 4), dim3(256), 0, stream, x, rn, sq, sqf, xnbf, N);

    int ntileM = (N + PM - 1) / PM;      // 79 row-tiles of 128
    int ntileN = (N + PN - 1) / PN;      // 40 col-tiles of 256
    int rows_per_xcd = (ntileM + 7) / 8; // 10
    int nblk = 8 * rows_per_xcd * CSPLIT; // 480 (pad blocks exit early)
    hipLaunchKernelGGL(gemm_prefilter, dim3(nblk), dim3(256), 0, stream,
                       xnbf, sqf, cand, cands, N, ntileM, ntileN);

    hipLaunchKernelGGL(rescore_topk, dim3((N + 3) / 4), dim3(256), 0, stream,
                       x, w, sq, cand, cands, (int*)d_out, N, k);
}